// Round 7
// baseline (216.128 us; speedup 1.0000x reference)
//
#include <hip/hip_runtime.h>

// LSTM autoencoder, fused, fp32 recurrence (no fp32 MFMA on CDNA4 -> VALU).
// D=64 H=16 L=8 B=4096 T=128.
//
// Mapping: wave = 1 batch, lane = gate row g = q*16+j (q: i,f,g,o; j: state).
// 1024 blocks x 256 thr = 4096 waves = 4 waves/SIMD (work-capped occupancy).
//
// Round-7 = round-6 RESUBMITTED UNCHANGED (round-6 bench died on an
// unresponsive container; kernel was never measured).
// Round-6 changes (on passing round-5): halve VALU issue with v_pk_fma_f32
// (VOP3P packed fp32, 2 FMA/instr — compiler never emits it from scalar fmaf):
//  - encoder GEMM inner loop: 2 pk_fma per (t,dc) instead of 4 fmaf.
//  - recurrence gate dot: 8 pk_fma (2 chains) + 3 adds instead of 16 fmaf.
//  - decoder gate + output projections: same treatment.
//  - h broadcast: all-lane write to a per-q copy (s_h4[wave][lane]) instead
//    of predicated q==0 write — no exec-mask flip; write = 2 lanes/bank
//    (free), read = per-q broadcast, 2-way bank alias (free).
//  - unchanged (round-3 failure proved necessary): ldsfence between h write
//    and broadcast read; stage fence; one-tile-ahead coalesced x prefetch.

constexpr int Dm = 64, Tm = 128, TB = 16;

typedef float v2f __attribute__((ext_vector_type(2)));

__device__ __forceinline__ v2f pkfma(v2f a, v2f b, v2f c) {
  v2f d;
  asm("v_pk_fma_f32 %0, %1, %2, %3" : "=v"(d) : "v"(a), "v"(b), "v"(c));
  return d;
}

__device__ __forceinline__ float fexp2(float x) {
#if __has_builtin(__builtin_amdgcn_exp2f)
  return __builtin_amdgcn_exp2f(x);
#else
  return exp2f(x);
#endif
}
__device__ __forceinline__ float frcp(float x) {
#if __has_builtin(__builtin_amdgcn_rcpf)
  return __builtin_amdgcn_rcpf(x);
#else
  return 1.0f / x;
#endif
}
__device__ __forceinline__ float tanh_(float x) {
  float xc = fminf(15.0f, fmaxf(-15.0f, x));
  float t = fexp2(2.88539008f * xc);       // e^(2x)
  return (t - 1.0f) * frcp(t + 1.0f);
}
// compiler+hw ordering for cross-lane LDS exchange (round-2/4-proven)
__device__ __forceinline__ void ldsfence() {
  asm volatile("s_waitcnt lgkmcnt(0)" ::: "memory");
}

__global__ __launch_bounds__(256, 4)
void lstm_ae_kernel(const float* __restrict__ x,
                    const float* __restrict__ eWih, const float* __restrict__ eWhh,
                    const float* __restrict__ eBih, const float* __restrict__ eBhh,
                    const float* __restrict__ Wl,   const float* __restrict__ bl,
                    const float* __restrict__ Wf,   const float* __restrict__ bf,
                    const float* __restrict__ dWih, const float* __restrict__ dWhh,
                    const float* __restrict__ dBih, const float* __restrict__ dBhh,
                    const float* __restrict__ Wo,   const float* __restrict__ bo,
                    float* __restrict__ out)
{
  __shared__ float s_wih[64 * 68];    // enc Wih rows padded to 68 floats
  __shared__ float s_x[4][TB * Dm];   // per-wave 4KB x tile
  __shared__ float s_h4[4][64];       // per-wave h broadcast, 4 q-copies
  __shared__ float s_wl[128];         // Wl [8][16]
  __shared__ float s_wf[128];         // Wf [16][8]

  const int tid = threadIdx.x;
  for (int i = tid; i < 4096; i += 256) s_wih[(i >> 6) * 68 + (i & 63)] = eWih[i];
  if (tid < 128) s_wl[tid] = Wl[tid];
  else s_wf[tid - 128] = Wf[tid - 128];
  __syncthreads();   // only block-wide sync

  const int wave = tid >> 6, lane = tid & 63;
  const int q = lane >> 4, j = lane & 15;
  const int b = blockIdx.x * 4 + wave;
  float* sxw = s_x[wave];
  float* hbq = &s_h4[wave][q * 16];   // this lane's q-copy of h

  // branch-free unified activation constants for THIS lane's gate:
  //   q==2 (g-gate, tanh): t=exp2(2/ln2 * x), av=(t-1)*rcp(t+1)
  //   else  (sigmoid)    : t=exp2(-1/ln2 * x), av= 1   *rcp(t+1)
  const float sAct = (q == 2) ? 2.88539008f : -1.44269504f;
  const float qgF  = (q == 2) ? 1.0f : 0.0f;   // num = qgF*t + cmF
  const float cmF  = (q == 2) ? -1.0f : 1.0f;
  const v2f z2 = {0.0f, 0.0f};

  // encoder per-gate constants in registers (as packed pairs)
  const v2f* wrp = (const v2f*)(eWhh + lane * 16);
  v2f wp0 = wrp[0], wp1 = wrp[1], wp2 = wrp[2], wp3 = wrp[3],
      wp4 = wrp[4], wp5 = wrp[5], wp6 = wrp[6], wp7 = wrp[7];
  const float biasg = eBih[lane] + eBhh[lane];

  float4 h0 = {0.f, 0.f, 0.f, 0.f}, h1 = h0, h2 = h0, h3 = h0;  // full h, replicated
  float cst = 0.0f;                                              // c[j], replicated per q
  const float* xb = x + (size_t)b * (Tm * Dm);

  // prefetch tile 0 (coalesced: 4 x 1KB per wave)
  float4 xs0 = *(const float4*)(xb + 0 * 256 + lane * 4);
  float4 xs1 = *(const float4*)(xb + 1 * 256 + lane * 4);
  float4 xs2 = *(const float4*)(xb + 2 * 256 + lane * 4);
  float4 xs3 = *(const float4*)(xb + 3 * 256 + lane * 4);

  // ================= encoder =================
#pragma unroll 1
  for (int tile = 0; tile < Tm / TB; ++tile) {
    // stage prefetched tile into LDS
    *(float4*)&sxw[0 * 256 + lane * 4] = xs0;
    *(float4*)&sxw[1 * 256 + lane * 4] = xs1;
    *(float4*)&sxw[2 * 256 + lane * 4] = xs2;
    *(float4*)&sxw[3 * 256 + lane * 4] = xs3;
    ldsfence();   // writes visible before uniform reads below

    // ---- input projection: xg[t][lane] for 16 timesteps, packed acc ----
    v2f acc2[TB];
#pragma unroll
    for (int t = 0; t < TB; ++t) acc2[t] = (v2f){biasg, 0.0f};
#pragma unroll 2
    for (int dc = 0; dc < 16; ++dc) {
      const float4 w4 = *(const float4*)&s_wih[lane * 68 + dc * 4];
      const v2f wA = {w4.x, w4.y}, wB = {w4.z, w4.w};
#pragma unroll
      for (int t = 0; t < TB; ++t) {
        const float4 x4 = *(const float4*)&sxw[t * 64 + dc * 4];  // uniform bcast
        const v2f xA = {x4.x, x4.y}, xB = {x4.z, x4.w};
        acc2[t] = pkfma(xA, wA, acc2[t]);
        acc2[t] = pkfma(xB, wB, acc2[t]);
      }
    }

    // issue next tile's loads; latency hides under the 16 recurrence steps
    if (tile < Tm / TB - 1) {
      const float* xt = xb + (tile + 1) * (TB * Dm);
      xs0 = *(const float4*)(xt + 0 * 256 + lane * 4);
      xs1 = *(const float4*)(xt + 1 * 256 + lane * 4);
      xs2 = *(const float4*)(xt + 2 * 256 + lane * 4);
      xs3 = *(const float4*)(xt + 3 * 256 + lane * 4);
    }

    // ---- recurrence over the 16 staged steps ----
#pragma unroll
    for (int tt = 0; tt < TB; ++tt) {
      const v2f p0 = {h0.x, h0.y}, p1 = {h0.z, h0.w};
      const v2f p2 = {h1.x, h1.y}, p3 = {h1.z, h1.w};
      const v2f p4 = {h2.x, h2.y}, p5 = {h2.z, h2.w};
      const v2f p6 = {h3.x, h3.y}, p7 = {h3.z, h3.w};
      v2f e0 = pkfma(p0, wp0, acc2[tt]);
      v2f e1 = pkfma(p1, wp1, z2);
      e0 = pkfma(p2, wp2, e0);  e1 = pkfma(p3, wp3, e1);
      e0 = pkfma(p4, wp4, e0);  e1 = pkfma(p5, wp5, e1);
      e0 = pkfma(p6, wp6, e0);  e1 = pkfma(p7, wp7, e1);
      const float gp = (e0.x + e0.y) + (e1.x + e1.y);
      // per-lane activation of OWN gate, then exchange activated values
      const float xc = fminf(15.0f, fmaxf(-15.0f, gp));
      const float t_ = fexp2(sAct * xc);
      const float av = fmaf(qgF, t_, cmF) * frcp(t_ + 1.0f);
      const float iv = __shfl(av, j);
      const float fv = __shfl(av, 16 + j);
      const float gv = __shfl(av, 32 + j);
      const float ov = __shfl(av, 48 + j);
      cst = fmaf(fv, cst, iv * gv);
      const float hv = ov * tanh_(cst);
      s_h4[wave][lane] = hv;   // all lanes write their q-copy (no divergence)
      ldsfence();              // h write -> broadcast read ordering
      h0 = *(const float4*)&hbq[0];
      h1 = *(const float4*)&hbq[4];
      h2 = *(const float4*)&hbq[8];
      h3 = *(const float4*)&hbq[12];
    }
  }

  // ================= latent -> rep -> decoder input gate (per lane) =================
  float lat[8];
#pragma unroll
  for (int l = 0; l < 8; ++l) {
    const float* wl4 = &s_wl[l * 16];
    float a = bl[l];
#pragma unroll
    for (int k = 0; k < 4; ++k) {
      const float4 wv = *(const float4*)&wl4[k * 4];
      const float4 hh = (k == 0) ? h0 : (k == 1) ? h1 : (k == 2) ? h2 : h3;
      a = fmaf(hh.x, wv.x, fmaf(hh.y, wv.y, fmaf(hh.z, wv.z, fmaf(hh.w, wv.w, a))));
    }
    lat[l] = a;
  }
  float rep[16];
#pragma unroll
  for (int k = 0; k < 16; ++k) {
    const float* wf8 = &s_wf[k * 8];
    float a = bf[k];
#pragma unroll
    for (int l = 0; l < 8; ++l) a = fmaf(lat[l], wf8[l], a);
    rep[k] = a;
  }
  const float* dwr = dWih + lane * 16;
  float dxg = dBih[lane] + dBhh[lane];
#pragma unroll
  for (int k = 0; k < 16; ++k) dxg = fmaf(rep[k], dwr[k], dxg);

  // ================= decoder + fused output projection =================
  {
    const v2f* dwp = (const v2f*)(dWhh + lane * 16);
    wp0 = dwp[0]; wp1 = dwp[1]; wp2 = dwp[2]; wp3 = dwp[3];
    wp4 = dwp[4]; wp5 = dwp[5]; wp6 = dwp[6]; wp7 = dwp[7];
  }
  const v2f* wop = (const v2f*)(Wo + lane * 16);
  const v2f op0 = wop[0], op1 = wop[1], op2 = wop[2], op3 = wop[3],
            op4 = wop[4], op5 = wop[5], op6 = wop[6], op7 = wop[7];
  const float bog = bo[lane];
  const v2f dx2 = {dxg, 0.0f};
  const v2f bg2 = {bog, 0.0f};

  h0 = h1 = h2 = h3 = make_float4(0.f, 0.f, 0.f, 0.f);
  cst = 0.0f;
  float* op = out + (size_t)b * (Tm * Dm) + lane;
#pragma unroll 1
  for (int t = 0; t < Tm; ++t) {
    const v2f p0 = {h0.x, h0.y}, p1 = {h0.z, h0.w};
    const v2f p2 = {h1.x, h1.y}, p3 = {h1.z, h1.w};
    const v2f p4 = {h2.x, h2.y}, p5 = {h2.z, h2.w};
    const v2f p6 = {h3.x, h3.y}, p7 = {h3.z, h3.w};
    v2f e0 = pkfma(p0, wp0, dx2);
    v2f e1 = pkfma(p1, wp1, z2);
    e0 = pkfma(p2, wp2, e0);  e1 = pkfma(p3, wp3, e1);
    e0 = pkfma(p4, wp4, e0);  e1 = pkfma(p5, wp5, e1);
    e0 = pkfma(p6, wp6, e0);  e1 = pkfma(p7, wp7, e1);
    const float gp = (e0.x + e0.y) + (e1.x + e1.y);
    const float xc = fminf(15.0f, fmaxf(-15.0f, gp));
    const float t_ = fexp2(sAct * xc);
    const float av = fmaf(qgF, t_, cmF) * frcp(t_ + 1.0f);
    const float iv = __shfl(av, j);
    const float fv = __shfl(av, 16 + j);
    const float gv = __shfl(av, 32 + j);
    const float ov = __shfl(av, 48 + j);
    // independent of the shfl results: project PREVIOUS h -> out[t-1]
    v2f f0 = pkfma(p0, op0, bg2);
    v2f f1 = pkfma(p1, op1, z2);
    f0 = pkfma(p2, op2, f0);  f1 = pkfma(p3, op3, f1);
    f0 = pkfma(p4, op4, f0);  f1 = pkfma(p5, op5, f1);
    f0 = pkfma(p6, op6, f0);  f1 = pkfma(p7, op7, f1);
    if (t) op[(t - 1) * 64] = (f0.x + f0.y) + (f1.x + f1.y);
    cst = fmaf(fv, cst, iv * gv);
    const float hv = ov * tanh_(cst);
    s_h4[wave][lane] = hv;   // all lanes write their q-copy
    ldsfence();              // h write -> broadcast read ordering
    h0 = *(const float4*)&hbq[0];
    h1 = *(const float4*)&hbq[4];
    h2 = *(const float4*)&hbq[8];
    h3 = *(const float4*)&hbq[12];
  }
  // final output row
  {
    const v2f p0 = {h0.x, h0.y}, p1 = {h0.z, h0.w};
    const v2f p2 = {h1.x, h1.y}, p3 = {h1.z, h1.w};
    const v2f p4 = {h2.x, h2.y}, p5 = {h2.z, h2.w};
    const v2f p6 = {h3.x, h3.y}, p7 = {h3.z, h3.w};
    v2f f0 = pkfma(p0, op0, bg2);
    v2f f1 = pkfma(p1, op1, z2);
    f0 = pkfma(p2, op2, f0);  f1 = pkfma(p3, op3, f1);
    f0 = pkfma(p4, op4, f0);  f1 = pkfma(p5, op5, f1);
    f0 = pkfma(p6, op6, f0);  f1 = pkfma(p7, op7, f1);
    op[(Tm - 1) * 64] = (f0.x + f0.y) + (f1.x + f1.y);
  }
}

extern "C" void kernel_launch(void* const* d_in, const int* in_sizes, int n_in,
                              void* d_out, int out_size, void* d_ws, size_t ws_size,
                              hipStream_t stream) {
  const float* x    = (const float*)d_in[0];
  const float* eWih = (const float*)d_in[1];
  const float* eWhh = (const float*)d_in[2];
  const float* eBih = (const float*)d_in[3];
  const float* eBhh = (const float*)d_in[4];
  const float* Wl   = (const float*)d_in[5];
  const float* bl   = (const float*)d_in[6];
  const float* Wf   = (const float*)d_in[7];
  const float* bf   = (const float*)d_in[8];
  const float* dWih = (const float*)d_in[9];
  const float* dWhh = (const float*)d_in[10];
  const float* dBih = (const float*)d_in[11];
  const float* dBhh = (const float*)d_in[12];
  const float* Wo   = (const float*)d_in[13];
  const float* bo   = (const float*)d_in[14];

  dim3 grid(1024), block(256);
  hipLaunchKernelGGL(lstm_ae_kernel, grid, block, 0, stream,
                     x, eWih, eWhh, eBih, eBhh, Wl, bl, Wf, bf,
                     dWih, dWhh, dBih, dBhh, Wo, bo, (float*)d_out);
}